// Round 2
// baseline (200.278 us; speedup 1.0000x reference)
//
#include <hip/hip_runtime.h>
#include <math.h>

#define FDIM 2048
#define GDIM 2048
#define NSIM 16
#define BATCH 32
#define FSPLIT 16   // f-tile = 128
#define GSPLIT 2    // 256 thr * 4 g * 2 = 2048
#define LOG2E 1.44269504088896340736f
#define LN2   0.69314718055994530942f

// Workspace (floats):
//  big path:  Lpart[FSPLIT][32][2048]  @ 0            (1048576 floats)
//  fallback:  Lsum [32][2048]          @ 0            (65536 floats, atomics+memset)
//  Mpart[4][32][256]                   @ LPART_END    (32768)
//  V[32][256]                          @ +32768       (8192)
//  w0eff[32][16]                       @ +8192        (512)

// ---------------------------------------------------------------------------
// Kernel A (hot): Lpart[fs][b][g] = sum_{f in tile} 2^( dot16(A[:,f], Tg') )
// where Tg' = T[:,g] * log2e.  grid (GSPLIT, FSPLIT, 32), block 256.
// ---------------------------------------------------------------------------
template <bool ATOMIC>
__global__ __launch_bounds__(256, 2) void kA(const float* __restrict__ data,
                                             const float* __restrict__ attn,
                                             float* __restrict__ Lout) {
    __shared__ float Al[128 * 16];  // [f][s], 8 KB
    const int tid = threadIdx.x;
    const int b  = blockIdx.z;
    const int fs = blockIdx.y;
    const int f0 = fs * 128;
    const int g0 = blockIdx.x * 1024 + tid * 4;

    // Stage A tile: Al[f][s] = data[(b*16+s)*FDIM + f0+f]
    const float* Ab = data + (size_t)b * NSIM * FDIM + f0;
#pragma unroll
    for (int k = 0; k < 8; ++k) {
        int e = k * 256 + tid;
        int s = e >> 7, f = e & 127;
        Al[f * 16 + s] = Ab[(size_t)s * FDIM + f];
    }

    // Loop-invariant T columns, pre-scaled by log2(e).
    const float* Tb = attn + (size_t)b * NSIM * GDIM + g0;
    float4 tg[NSIM];
#pragma unroll
    for (int s = 0; s < NSIM; ++s) {
        float4 v = *(const float4*)(Tb + (size_t)s * GDIM);
        v.x *= LOG2E; v.y *= LOG2E; v.z *= LOG2E; v.w *= LOG2E;
        tg[s] = v;
    }
    __syncthreads();

    float s0 = 0.f, s1 = 0.f, s2 = 0.f, s3 = 0.f;
#pragma unroll 8
    for (int fi = 0; fi < 128; ++fi) {
        const float4* ap = (const float4*)(Al + fi * 16);
        float4 a0 = ap[0], a1 = ap[1], a2 = ap[2], a3 = ap[3];
        float d0, d1, d2, d3;
        d0 = a0.x * tg[0].x;  d1 = a0.x * tg[0].y;  d2 = a0.x * tg[0].z;  d3 = a0.x * tg[0].w;
        d0 += a0.y * tg[1].x; d1 += a0.y * tg[1].y; d2 += a0.y * tg[1].z; d3 += a0.y * tg[1].w;
        d0 += a0.z * tg[2].x; d1 += a0.z * tg[2].y; d2 += a0.z * tg[2].z; d3 += a0.z * tg[2].w;
        d0 += a0.w * tg[3].x; d1 += a0.w * tg[3].y; d2 += a0.w * tg[3].z; d3 += a0.w * tg[3].w;
        d0 += a1.x * tg[4].x; d1 += a1.x * tg[4].y; d2 += a1.x * tg[4].z; d3 += a1.x * tg[4].w;
        d0 += a1.y * tg[5].x; d1 += a1.y * tg[5].y; d2 += a1.y * tg[5].z; d3 += a1.y * tg[5].w;
        d0 += a1.z * tg[6].x; d1 += a1.z * tg[6].y; d2 += a1.z * tg[6].z; d3 += a1.z * tg[6].w;
        d0 += a1.w * tg[7].x; d1 += a1.w * tg[7].y; d2 += a1.w * tg[7].z; d3 += a1.w * tg[7].w;
        d0 += a2.x * tg[8].x; d1 += a2.x * tg[8].y; d2 += a2.x * tg[8].z; d3 += a2.x * tg[8].w;
        d0 += a2.y * tg[9].x; d1 += a2.y * tg[9].y; d2 += a2.y * tg[9].z; d3 += a2.y * tg[9].w;
        d0 += a2.z * tg[10].x; d1 += a2.z * tg[10].y; d2 += a2.z * tg[10].z; d3 += a2.z * tg[10].w;
        d0 += a2.w * tg[11].x; d1 += a2.w * tg[11].y; d2 += a2.w * tg[11].z; d3 += a2.w * tg[11].w;
        d0 += a3.x * tg[12].x; d1 += a3.x * tg[12].y; d2 += a3.x * tg[12].z; d3 += a3.x * tg[12].w;
        d0 += a3.y * tg[13].x; d1 += a3.y * tg[13].y; d2 += a3.y * tg[13].z; d3 += a3.y * tg[13].w;
        d0 += a3.z * tg[14].x; d1 += a3.z * tg[14].y; d2 += a3.z * tg[14].z; d3 += a3.z * tg[14].w;
        d0 += a3.w * tg[15].x; d1 += a3.w * tg[15].y; d2 += a3.w * tg[15].z; d3 += a3.w * tg[15].w;
        s0 += __builtin_amdgcn_exp2f(d0);
        s1 += __builtin_amdgcn_exp2f(d1);
        s2 += __builtin_amdgcn_exp2f(d2);
        s3 += __builtin_amdgcn_exp2f(d3);
    }
    if (ATOMIC) {
        float* Lp = Lout + (size_t)b * GDIM + g0;
        atomicAdd(Lp + 0, s0);
        atomicAdd(Lp + 1, s1);
        atomicAdd(Lp + 2, s2);
        atomicAdd(Lp + 3, s3);
    } else {
        float* Lp = Lout + ((size_t)fs * BATCH + b) * GDIM + g0;
        *(float4*)Lp = make_float4(s0, s1, s2, s3);
    }
}

// ---------------------------------------------------------------------------
// kMpart: Mpart[gs][b][s*16+t] = sum_{g in 512-chunk} T[s,g]T[t,g]
// grid (4, 32), block 256.
// ---------------------------------------------------------------------------
#define TPAD 516  // *4B = 2064 (16B aligned); t*516 % 32 banks -> 2-way max (free)
__global__ __launch_bounds__(256) void kMpart(const float* __restrict__ attn,
                                              float* __restrict__ Mpart) {
    __shared__ float Tl[NSIM * TPAD];
    const int tid = threadIdx.x;
    const int b  = blockIdx.y;
    const int g0 = blockIdx.x * 512;
    const float* Tb = attn + (size_t)b * NSIM * GDIM + g0;
#pragma unroll
    for (int k = 0; k < 32; ++k) {
        int e = k * 256 + tid;
        int s = e >> 9, g = e & 511;
        Tl[s * TPAD + g] = Tb[(size_t)s * GDIM + g];
    }
    __syncthreads();
    const int s = tid >> 4, t = tid & 15;
    const float* ps = Tl + s * TPAD;
    const float* pt = Tl + t * TPAD;
    float acc = 0.f;
#pragma unroll 4
    for (int q = 0; q < 128; ++q) {
        float4 x = *(const float4*)(ps + q * 4);
        float4 y = *(const float4*)(pt + q * 4);
        acc += x.x * y.x + x.y * y.y + x.z * y.z + x.w * y.w;
    }
    Mpart[((size_t)blockIdx.x * BATCH + b) * 256 + tid] = acc;
}

// ---------------------------------------------------------------------------
// kBall: fuse L = ln2*log2(sum of Lpart), c[t] = sum_g L[g]T[t,g],
//        M fold -> V[s][j], w0eff[j].  grid (32), block 256.
// ---------------------------------------------------------------------------
__global__ __launch_bounds__(256) void kBall(const float* __restrict__ attn,
                                             const float* __restrict__ Lpart, int nparts,
                                             const float* __restrict__ Mpart,
                                             const float* __restrict__ W,
                                             const float* __restrict__ bias,
                                             float* __restrict__ V,
                                             float* __restrict__ w0eff) {
    __shared__ float Ll[GDIM];       // 8 KB
    __shared__ float Msh[256];
    __shared__ float red[16][17];
    __shared__ float cl[16];
    const int tid = threadIdx.x;
    const int b = blockIdx.x;

    // L[g]
#pragma unroll
    for (int k = 0; k < 8; ++k) {
        int g = k * 256 + tid;
        float sum = 0.f;
        for (int p = 0; p < nparts; ++p)
            sum += Lpart[((size_t)p * BATCH + b) * GDIM + g];
        Ll[g] = LN2 * __builtin_amdgcn_logf(sum);
    }
    // M[s][t] = sum of 4 partials
    {
        float m = 0.f;
#pragma unroll
        for (int p = 0; p < 4; ++p)
            m += Mpart[((size_t)p * BATCH + b) * 256 + tid];
        Msh[tid] = m;
    }
    __syncthreads();

    // c partials: thread (seg = tid>>4, t = tid&15) over g in [seg*128, seg*128+128)
    {
        const int t = tid & 15, seg = tid >> 4;
        const float* Trow = attn + (size_t)(b * NSIM + t) * GDIM + seg * 128;
        const float* Lseg = Ll + seg * 128;
        float acc = 0.f;
#pragma unroll 4
        for (int q = 0; q < 32; ++q) {
            float4 l = *(const float4*)(Lseg + q * 4);
            float4 tv = *(const float4*)(Trow + q * 4);
            acc += l.x * tv.x + l.y * tv.y + l.z * tv.z + l.w * tv.w;
        }
        red[t][seg] = acc;
    }
    __syncthreads();
    if (tid < 16) {
        float s = 0.f;
#pragma unroll
        for (int k = 0; k < 16; ++k) s += red[tid][k];
        cl[tid] = s;
    }
    __syncthreads();

    // V[s][j] and w0eff[j]
    {
        const int s = tid >> 4, j = tid & 15;
        float acc = 0.f;
#pragma unroll
        for (int t = 0; t < 16; ++t) acc += Msh[s * 16 + t] * W[j * 32 + t];
        V[(size_t)b * 256 + s * 16 + j] = acc + W[j * 32 + 16 + s];
        if (s == 0) {
            float w0 = 0.f;
#pragma unroll
            for (int t = 0; t < 16; ++t) w0 += cl[t] * W[j * 32 + t];
            w0eff[b * 16 + j] = bias[j] - w0;
        }
    }
}

// ---------------------------------------------------------------------------
// kC: epilogue. grid (8, 32), block 256.
// ---------------------------------------------------------------------------
__global__ __launch_bounds__(256) void kC(const float* __restrict__ data,
                                          const float* __restrict__ V,
                                          const float* __restrict__ w0eff,
                                          float* __restrict__ out) {
    const int tid = threadIdx.x;
    const int b = blockIdx.y;
    const int f = blockIdx.x * 256 + tid;
    float As[NSIM];
#pragma unroll
    for (int s = 0; s < NSIM; ++s)
        As[s] = data[(size_t)(b * NSIM + s) * FDIM + f];
    const float* Vb = V + (size_t)b * 256;
    const float* w0 = w0eff + b * 16;
#pragma unroll
    for (int j = 0; j < NSIM; ++j) {
        float p = w0[j];
#pragma unroll
        for (int s = 0; s < NSIM; ++s) p += As[s] * Vb[s * 16 + j];
        float e = __builtin_amdgcn_exp2f(-LOG2E * p);
        float gate = __builtin_amdgcn_rcpf(1.0f + e);
        size_t r = (size_t)(j * 32 + b) * FDIM + f;
        out[r] = gate * data[r];
    }
}

extern "C" void kernel_launch(void* const* d_in, const int* in_sizes, int n_in,
                              void* d_out, int out_size, void* d_ws, size_t ws_size,
                              hipStream_t stream) {
    const float* data = (const float*)d_in[0];
    const float* attn = (const float*)d_in[1];
    const float* W    = (const float*)d_in[2];
    const float* bias = (const float*)d_in[3];
    float* out = (float*)d_out;
    float* ws  = (float*)d_ws;

    const size_t LPART_FLOATS = (size_t)FSPLIT * BATCH * GDIM;  // 1 Mi floats
    const bool big = ws_size >= (LPART_FLOATS + 32768 + 8192 + 512) * sizeof(float);

    if (big) {
        float* Lpart = ws;
        float* Mpart = ws + LPART_FLOATS;
        float* V     = Mpart + 32768;
        float* w0eff = V + 8192;
        kA<false><<<dim3(GSPLIT, FSPLIT, BATCH), 256, 0, stream>>>(data, attn, Lpart);
        kMpart<<<dim3(4, BATCH), 256, 0, stream>>>(attn, Mpart);
        kBall<<<dim3(BATCH), 256, 0, stream>>>(attn, Lpart, FSPLIT, Mpart, W, bias, V, w0eff);
        kC<<<dim3(8, BATCH), 256, 0, stream>>>(data, V, w0eff, out);
    } else {
        float* Lsum  = ws;                  // 65536
        float* Mpart = ws + 65536;
        float* V     = Mpart + 32768;
        float* w0eff = V + 8192;
        hipMemsetAsync(Lsum, 0, 65536 * sizeof(float), stream);
        kA<true><<<dim3(GSPLIT, FSPLIT, BATCH), 256, 0, stream>>>(data, attn, Lsum);
        kMpart<<<dim3(4, BATCH), 256, 0, stream>>>(attn, Mpart);
        kBall<<<dim3(BATCH), 256, 0, stream>>>(attn, Lsum, 1, Mpart, W, bias, V, w0eff);
        kC<<<dim3(8, BATCH), 256, 0, stream>>>(data, V, w0eff, out);
    }
}

// Round 3
// 111.808 us; speedup vs baseline: 1.7913x; 1.7913x over previous
//
#include <hip/hip_runtime.h>
#include <math.h>

#define LOG2E 1.44269504088896340736f
#define LN2   0.69314718055994530942f

typedef _Float16 half8 __attribute__((ext_vector_type(8)));
typedef float f32x4v __attribute__((ext_vector_type(4)));

#define AROW 24   // halves per LDS row (48B): 16B-aligned frag reads, conflict-free

// ---------------------------------------------------------------------------
// kA: Lout[fb][b][g] = sum_{f in 1024-range} exp( dot16(A[:,f], T[:,g]) )
// via mfma_f32_16x16x32_f16 with [Ah|Al] x [Th|Th] + [Ah|Al] x [Tl|0].
// grid (16 gb, 2 fb, 32 b), block 256 (4 waves; wave owns 32 g-columns).
// ---------------------------------------------------------------------------
template <bool ATOMIC>
__global__ __launch_bounds__(256, 4) void kA(const float* __restrict__ data,
                                             const float* __restrict__ attn,
                                             float* __restrict__ Lout) {
    __shared__ _Float16 AhB[128 * AROW];
    __shared__ _Float16 AlB[128 * AROW];
    const int tid = threadIdx.x;
    const int b = blockIdx.z, fb = blockIdx.y, gb = blockIdx.x;
    const int wave = tid >> 6, lane = tid & 63;
    const int n = lane & 15, q = lane >> 4;
    const int s0 = (q & 1) * 8;

    // B fragments (loop-invariant). B[k=q*8+j][n=lane&15]; k mod 16 = s0+j.
    const float* Tb = attn + (size_t)b * 16 * 2048;
    half8 B1[2], B2[2];
#pragma unroll
    for (int ct = 0; ct < 2; ++ct) {
        const int g = gb * 128 + wave * 32 + ct * 16 + n;
        half8 bh, bl;
#pragma unroll
        for (int j = 0; j < 8; ++j) {
            float x = Tb[(size_t)(s0 + j) * 2048 + g] * LOG2E;
            _Float16 h = (_Float16)x;
            _Float16 l = (_Float16)(x - (float)h);
            bh[j] = h;
            bl[j] = (q < 2) ? l : (_Float16)0.0f;
        }
        B1[ct] = bh;
        B2[ct] = bl;
    }

    f32x4v cs0 = {0.f, 0.f, 0.f, 0.f}, cs1 = {0.f, 0.f, 0.f, 0.f};

    const float* Ab = data + (size_t)b * 16 * 2048 + fb * 1024;
    const int fst = tid >> 1;        // staging: 2 threads per f-row
    const int sh  = (tid & 1) * 8;   // each covers 8 s-values
    // A-frag pointer: m = lane&15 (f-row in tile), k = q*8+j -> hi buf q<2, s-off (q&1)*8
    const _Float16* aptr = ((q < 2) ? AhB : AlB) + n * AROW + s0;

    for (int chunk = 0; chunk < 8; ++chunk) {
        const float* Ac = Ab + chunk * 128;
        _Float16 hb[8], lb[8];
#pragma unroll
        for (int j = 0; j < 8; ++j) {
            float x = Ac[(size_t)(sh + j) * 2048 + fst];
            _Float16 h = (_Float16)x;
            hb[j] = h;
            lb[j] = (_Float16)(x - (float)h);
        }
        __syncthreads();  // previous chunk's compute done
        half8 hv, lv;
#pragma unroll
        for (int j = 0; j < 8; ++j) { hv[j] = hb[j]; lv[j] = lb[j]; }
        *(half8*)(AhB + fst * AROW + sh) = hv;
        *(half8*)(AlB + fst * AROW + sh) = lv;
        __syncthreads();

#pragma unroll
        for (int rt = 0; rt < 8; ++rt) {
            half8 af = *(const half8*)(aptr + rt * 16 * AROW);
            f32x4v C = {0.f, 0.f, 0.f, 0.f};
            C = __builtin_amdgcn_mfma_f32_16x16x32_f16(af, B1[0], C, 0, 0, 0);
            C = __builtin_amdgcn_mfma_f32_16x16x32_f16(af, B2[0], C, 0, 0, 0);
            cs0[0] += __builtin_amdgcn_exp2f(C[0]);
            cs0[1] += __builtin_amdgcn_exp2f(C[1]);
            cs0[2] += __builtin_amdgcn_exp2f(C[2]);
            cs0[3] += __builtin_amdgcn_exp2f(C[3]);
            f32x4v D = {0.f, 0.f, 0.f, 0.f};
            D = __builtin_amdgcn_mfma_f32_16x16x32_f16(af, B1[1], D, 0, 0, 0);
            D = __builtin_amdgcn_mfma_f32_16x16x32_f16(af, B2[1], D, 0, 0, 0);
            cs1[0] += __builtin_amdgcn_exp2f(D[0]);
            cs1[1] += __builtin_amdgcn_exp2f(D[1]);
            cs1[2] += __builtin_amdgcn_exp2f(D[2]);
            cs1[3] += __builtin_amdgcn_exp2f(D[3]);
        }
    }

    float v0 = cs0[0] + cs0[1] + cs0[2] + cs0[3];
    float v1 = cs1[0] + cs1[1] + cs1[2] + cs1[3];
    v0 += __shfl_xor(v0, 16);
    v0 += __shfl_xor(v0, 32);
    v1 += __shfl_xor(v1, 16);
    v1 += __shfl_xor(v1, 32);
    if (q == 0) {
        const int g = gb * 128 + wave * 32 + n;
        if (ATOMIC) {
            atomicAdd(&Lout[(size_t)b * 2048 + g], v0);
            atomicAdd(&Lout[(size_t)b * 2048 + g + 16], v1);
        } else {
            Lout[((size_t)fb * 32 + b) * 2048 + g] = v0;
            Lout[((size_t)fb * 32 + b) * 2048 + g + 16] = v1;
        }
    }
}

// ---------------------------------------------------------------------------
// kTail: per (seg of 512 g, b): L = ln2*log2(sum Lpart), c-partials, M-partials.
// grid (4, 32), block 256.
// ---------------------------------------------------------------------------
#define TPAD 516
__global__ __launch_bounds__(256) void kTail(const float* __restrict__ attn,
                                             const float* __restrict__ Lpart, int nparts,
                                             float* __restrict__ Mpart,
                                             float* __restrict__ cpart) {
    __shared__ float Tsh[16 * TPAD];  // 33 KB
    __shared__ float Lsh[512];
    __shared__ float red[16][17];
    const int tid = threadIdx.x;
    const int seg = blockIdx.x, b = blockIdx.y;
    const int g0 = seg * 512;

#pragma unroll
    for (int k = 0; k < 32; ++k) {
        int e = k * 256 + tid;
        int s = e >> 9, g = e & 511;
        Tsh[s * TPAD + g] = attn[(size_t)(b * 16 + s) * 2048 + g0 + g];
    }
#pragma unroll
    for (int k = 0; k < 2; ++k) {
        int g = k * 256 + tid;
        float sum = 0.f;
        for (int p = 0; p < nparts; ++p)
            sum += Lpart[((size_t)p * 32 + b) * 2048 + g0 + g];
        Lsh[g] = LN2 * __builtin_amdgcn_logf(sum);
    }
    __syncthreads();

    // c-partial: t = tid&15 over g-subrange of 32
    {
        const int t = tid & 15, i = tid >> 4;
        float acc = 0.f;
#pragma unroll
        for (int k = 0; k < 8; ++k) {
            float4 l  = *(const float4*)(Lsh + i * 32 + k * 4);
            float4 tv = *(const float4*)(Tsh + t * TPAD + i * 32 + k * 4);
            acc += l.x * tv.x + l.y * tv.y + l.z * tv.z + l.w * tv.w;
        }
        red[t][i] = acc;
    }
    __syncthreads();
    if (tid < 16) {
        float s = 0.f;
#pragma unroll
        for (int k = 0; k < 16; ++k) s += red[tid][k];
        cpart[((size_t)seg * 32 + b) * 16 + tid] = s;
    }

    // M-partial: thread = (s,t)
    {
        const int s = tid >> 4, t = tid & 15;
        float acc = 0.f;
#pragma unroll 4
        for (int qk = 0; qk < 128; ++qk) {
            float4 x = *(const float4*)(Tsh + s * TPAD + qk * 4);
            float4 y = *(const float4*)(Tsh + t * TPAD + qk * 4);
            acc += x.x * y.x + x.y * y.y + x.z * y.z + x.w * y.w;
        }
        Mpart[((size_t)seg * 32 + b) * 256 + tid] = acc;
    }
}

// ---------------------------------------------------------------------------
// kFold: fold 4 M/c partials with W, bias -> V, w0eff. grid (32), block 256.
// ---------------------------------------------------------------------------
__global__ __launch_bounds__(256) void kFold(const float* __restrict__ Mpart,
                                             const float* __restrict__ cpart,
                                             const float* __restrict__ W,
                                             const float* __restrict__ bias,
                                             float* __restrict__ V,
                                             float* __restrict__ w0eff) {
    __shared__ float Msh[256];
    __shared__ float cl[16];
    const int b = blockIdx.x, tid = threadIdx.x;
    float m = 0.f;
#pragma unroll
    for (int p = 0; p < 4; ++p) m += Mpart[((size_t)p * 32 + b) * 256 + tid];
    Msh[tid] = m;
    if (tid < 16) {
        float c = 0.f;
#pragma unroll
        for (int p = 0; p < 4; ++p) c += cpart[((size_t)p * 32 + b) * 16 + tid];
        cl[tid] = c;
    }
    __syncthreads();
    const int s = tid >> 4, j = tid & 15;
    float acc = 0.f;
#pragma unroll
    for (int t = 0; t < 16; ++t) acc += Msh[s * 16 + t] * W[j * 32 + t];
    V[(size_t)b * 256 + s * 16 + j] = acc + W[j * 32 + 16 + s];
    if (s == 0) {
        float w0 = 0.f;
#pragma unroll
        for (int t = 0; t < 16; ++t) w0 += cl[t] * W[j * 32 + t];
        w0eff[b * 16 + j] = bias[j] - w0;
    }
}

// ---------------------------------------------------------------------------
// kC: epilogue. grid (8, 32), block 256.
// ---------------------------------------------------------------------------
__global__ __launch_bounds__(256) void kC(const float* __restrict__ data,
                                          const float* __restrict__ V,
                                          const float* __restrict__ w0eff,
                                          float* __restrict__ out) {
    const int tid = threadIdx.x;
    const int b = blockIdx.y;
    const int f = blockIdx.x * 256 + tid;
    float As[16];
#pragma unroll
    for (int s = 0; s < 16; ++s)
        As[s] = data[(size_t)(b * 16 + s) * 2048 + f];
    const float* Vb = V + (size_t)b * 256;
    const float* w0 = w0eff + b * 16;
#pragma unroll
    for (int j = 0; j < 16; ++j) {
        float p = w0[j];
#pragma unroll
        for (int s = 0; s < 16; ++s) p += As[s] * Vb[s * 16 + j];
        float e = __builtin_amdgcn_exp2f(-LOG2E * p);
        float gate = __builtin_amdgcn_rcpf(1.0f + e);
        size_t r = (size_t)(j * 32 + b) * 2048 + f;
        out[r] = gate * data[r];
    }
}

extern "C" void kernel_launch(void* const* d_in, const int* in_sizes, int n_in,
                              void* d_out, int out_size, void* d_ws, size_t ws_size,
                              hipStream_t stream) {
    const float* data = (const float*)d_in[0];
    const float* attn = (const float*)d_in[1];
    const float* W    = (const float*)d_in[2];
    const float* bias = (const float*)d_in[3];
    float* out = (float*)d_out;
    float* ws  = (float*)d_ws;

    // big layout: Lpart[2][32][2048] | Mpart[4][32][256] | cpart[4][32][16] | V | w0eff
    const size_t LP = 2 * 32 * 2048;              // 131072
    const size_t need_big = LP + 32768 + 2048 + 8192 + 512;

    if (ws_size >= need_big * sizeof(float)) {
        float* Lpart = ws;
        float* Mpart = ws + LP;
        float* cpart = Mpart + 32768;
        float* V     = cpart + 2048;
        float* w0eff = V + 8192;
        kA<false><<<dim3(16, 2, 32), 256, 0, stream>>>(data, attn, Lpart);
        kTail<<<dim3(4, 32), 256, 0, stream>>>(attn, Lpart, 2, Mpart, cpart);
        kFold<<<dim3(32), 256, 0, stream>>>(Mpart, cpart, W, bias, V, w0eff);
        kC<<<dim3(8, 32), 256, 0, stream>>>(data, V, w0eff, out);
    } else {
        float* Lsum  = ws;            // 65536
        float* Mpart = ws + 65536;
        float* cpart = Mpart + 32768;
        float* V     = cpart + 2048;
        float* w0eff = V + 8192;
        hipMemsetAsync(Lsum, 0, 65536 * sizeof(float), stream);
        kA<true><<<dim3(16, 2, 32), 256, 0, stream>>>(data, attn, Lsum);
        kTail<<<dim3(4, 32), 256, 0, stream>>>(attn, Lsum, 1, Mpart, cpart);
        kFold<<<dim3(32), 256, 0, stream>>>(Mpart, cpart, W, bias, V, w0eff);
        kC<<<dim3(8, 32), 256, 0, stream>>>(data, V, w0eff, out);
    }
}

// Round 4
// 94.989 us; speedup vs baseline: 2.1084x; 1.1771x over previous
//
#include <hip/hip_runtime.h>
#include <math.h>

#define LOG2E 1.44269504088896340736f
#define LN2   0.69314718055994530942f

typedef _Float16 half8 __attribute__((ext_vector_type(8)));
typedef float f32x4v __attribute__((ext_vector_type(4)));

#define AROW 24   // halves per LDS row (48B): 16B-aligned frag reads

// ---------------------------------------------------------------------------
// kA: Lout[fb][b][g] = sum_{f in 512-range} exp( dot16(A[:,f], T[:,g]) )
// via mfma_f32_16x16x32_f16 with [Ah|Al] x [Th|Th] + [Ah|Al] x [Tl|0].
// grid (16 gb, 4 fb, 32 b), block 256 (4 waves; wave owns 32 g-columns).
// 2048 blocks = 8 blocks/CU -> up to 32 waves/CU at VGPR<=64.
// ---------------------------------------------------------------------------
template <bool ATOMIC>
__global__ __launch_bounds__(256, 4) void kA(const float* __restrict__ data,
                                             const float* __restrict__ attn,
                                             float* __restrict__ Lout) {
    __shared__ _Float16 AhB[128 * AROW];
    __shared__ _Float16 AlB[128 * AROW];
    const int tid = threadIdx.x;
    const int b = blockIdx.z, fb = blockIdx.y, gb = blockIdx.x;
    const int wave = tid >> 6, lane = tid & 63;
    const int n = lane & 15, q = lane >> 4;
    const int s0 = (q & 1) * 8;

    // B fragments (loop-invariant). B[k=q*8+j][n]; k mod 16 = s0+j.
    const float* Tb = attn + (size_t)b * 16 * 2048;
    half8 B1[2], B2[2];
#pragma unroll
    for (int ct = 0; ct < 2; ++ct) {
        const int g = gb * 128 + wave * 32 + ct * 16 + n;
        half8 bh, bl;
#pragma unroll
        for (int j = 0; j < 8; ++j) {
            float x = Tb[(size_t)(s0 + j) * 2048 + g] * LOG2E;
            _Float16 h = (_Float16)x;
            _Float16 l = (_Float16)(x - (float)h);
            bh[j] = h;
            bl[j] = (q < 2) ? l : (_Float16)0.0f;
        }
        B1[ct] = bh;
        B2[ct] = bl;
    }

    f32x4v cs0 = {0.f, 0.f, 0.f, 0.f}, cs1 = {0.f, 0.f, 0.f, 0.f};

    const float* Ab = data + (size_t)b * 16 * 2048 + fb * 512;
    const int fst = tid & 127;       // f-row within tile (wave-consecutive)
    const int sh  = (tid >> 7) * 8;  // s-half
    const _Float16* aptr = ((q < 2) ? AhB : AlB) + n * AROW + s0;

    for (int chunk = 0; chunk < 4; ++chunk) {
        const float* Ac = Ab + chunk * 128;
        _Float16 hb[8], lb[8];
#pragma unroll
        for (int j = 0; j < 8; ++j) {
            float x = Ac[(size_t)(sh + j) * 2048 + fst];
            _Float16 h = (_Float16)x;
            hb[j] = h;
            lb[j] = (_Float16)(x - (float)h);
        }
        __syncthreads();  // previous chunk's compute done
        half8 hv, lv;
#pragma unroll
        for (int j = 0; j < 8; ++j) { hv[j] = hb[j]; lv[j] = lb[j]; }
        *(half8*)(AhB + fst * AROW + sh) = hv;
        *(half8*)(AlB + fst * AROW + sh) = lv;
        __syncthreads();

#pragma unroll
        for (int rt = 0; rt < 8; ++rt) {
            half8 af = *(const half8*)(aptr + rt * 16 * AROW);
            f32x4v C = {0.f, 0.f, 0.f, 0.f};
            C = __builtin_amdgcn_mfma_f32_16x16x32_f16(af, B1[0], C, 0, 0, 0);
            C = __builtin_amdgcn_mfma_f32_16x16x32_f16(af, B2[0], C, 0, 0, 0);
            cs0[0] += __builtin_amdgcn_exp2f(C[0]);
            cs0[1] += __builtin_amdgcn_exp2f(C[1]);
            cs0[2] += __builtin_amdgcn_exp2f(C[2]);
            cs0[3] += __builtin_amdgcn_exp2f(C[3]);
            f32x4v D = {0.f, 0.f, 0.f, 0.f};
            D = __builtin_amdgcn_mfma_f32_16x16x32_f16(af, B1[1], D, 0, 0, 0);
            D = __builtin_amdgcn_mfma_f32_16x16x32_f16(af, B2[1], D, 0, 0, 0);
            cs1[0] += __builtin_amdgcn_exp2f(D[0]);
            cs1[1] += __builtin_amdgcn_exp2f(D[1]);
            cs1[2] += __builtin_amdgcn_exp2f(D[2]);
            cs1[3] += __builtin_amdgcn_exp2f(D[3]);
        }
    }

    float v0 = cs0[0] + cs0[1] + cs0[2] + cs0[3];
    float v1 = cs1[0] + cs1[1] + cs1[2] + cs1[3];
    v0 += __shfl_xor(v0, 16);
    v0 += __shfl_xor(v0, 32);
    v1 += __shfl_xor(v1, 16);
    v1 += __shfl_xor(v1, 32);
    if (q == 0) {
        const int g = gb * 128 + wave * 32 + n;
        if (ATOMIC) {
            atomicAdd(&Lout[(size_t)b * 2048 + g], v0);
            atomicAdd(&Lout[(size_t)b * 2048 + g + 16], v1);
        } else {
            Lout[((size_t)fb * 32 + b) * 2048 + g] = v0;
            Lout[((size_t)fb * 32 + b) * 2048 + g + 16] = v1;
        }
    }
}

// ---------------------------------------------------------------------------
// kTail: per (256-g segment, b): L = ln2*log2(sum Lpart), c-partials, M-partials.
// grid (8, 32), block 256.
// ---------------------------------------------------------------------------
#define TP 260
__global__ __launch_bounds__(256) void kTail(const float* __restrict__ attn,
                                             const float* __restrict__ Lpart, int nparts,
                                             float* __restrict__ Mpart,
                                             float* __restrict__ cpart) {
    __shared__ float Tsh[16 * TP];   // 16.6 KB
    __shared__ float Lsh[256];
    __shared__ float red[16][17];
    const int tid = threadIdx.x;
    const int seg = blockIdx.x, b = blockIdx.y;
    const int g0 = seg * 256;

#pragma unroll
    for (int s = 0; s < 16; ++s)
        Tsh[s * TP + tid] = attn[(size_t)(b * 16 + s) * 2048 + g0 + tid];
    {
        float sum = 0.f;
        for (int p = 0; p < nparts; ++p)
            sum += Lpart[((size_t)p * 32 + b) * 2048 + g0 + tid];
        Lsh[tid] = LN2 * __builtin_amdgcn_logf(sum);
    }
    __syncthreads();

    // c-partial: t = tid&15 over a 16-g subrange
    {
        const int t = tid & 15, i = tid >> 4;
        float acc = 0.f;
#pragma unroll
        for (int k = 0; k < 4; ++k) {
            float4 l  = *(const float4*)(Lsh + i * 16 + k * 4);
            float4 tv = *(const float4*)(Tsh + t * TP + i * 16 + k * 4);
            acc += l.x * tv.x + l.y * tv.y + l.z * tv.z + l.w * tv.w;
        }
        red[t][i] = acc;
    }
    __syncthreads();
    if (tid < 16) {
        float s = 0.f;
#pragma unroll
        for (int k = 0; k < 16; ++k) s += red[tid][k];
        cpart[((size_t)seg * 32 + b) * 16 + tid] = s;
    }

    // M-partial: thread = (s,t)
    {
        const int s = tid >> 4, t = tid & 15;
        float a0 = 0.f, a1 = 0.f;
#pragma unroll 4
        for (int qk = 0; qk < 32; ++qk) {
            float4 x = *(const float4*)(Tsh + s * TP + qk * 8);
            float4 y = *(const float4*)(Tsh + t * TP + qk * 8);
            a0 += x.x * y.x + x.y * y.y + x.z * y.z + x.w * y.w;
            float4 x2 = *(const float4*)(Tsh + s * TP + qk * 8 + 4);
            float4 y2 = *(const float4*)(Tsh + t * TP + qk * 8 + 4);
            a1 += x2.x * y2.x + x2.y * y2.y + x2.z * y2.z + x2.w * y2.w;
        }
        Mpart[((size_t)seg * 32 + b) * 256 + tid] = a0 + a1;
    }
}

// ---------------------------------------------------------------------------
// kC2: fold M/c partials with W,bias (redundant per block, cheap) + epilogue.
// grid (8, 32), block 256.
// ---------------------------------------------------------------------------
__global__ __launch_bounds__(256) void kC2(const float* __restrict__ data,
                                           const float* __restrict__ Mpart,
                                           const float* __restrict__ cpart,
                                           const float* __restrict__ W,
                                           const float* __restrict__ bias,
                                           float* __restrict__ out) {
    __shared__ float Msh[256];
    __shared__ float csh[16];
    __shared__ float Vsh[256];
    __shared__ float w0sh[16];
    const int tid = threadIdx.x;
    const int b = blockIdx.y;
    const int f = blockIdx.x * 256 + tid;

    {
        float m = 0.f;
#pragma unroll
        for (int p = 0; p < 8; ++p) m += Mpart[((size_t)p * 32 + b) * 256 + tid];
        Msh[tid] = m;
        if (tid < 16) {
            float c = 0.f;
#pragma unroll
            for (int p = 0; p < 8; ++p) c += cpart[((size_t)p * 32 + b) * 16 + tid];
            csh[tid] = c;
        }
    }
    __syncthreads();
    {
        const int s = tid >> 4, j = tid & 15;
        float acc = 0.f;
#pragma unroll
        for (int t = 0; t < 16; ++t) acc += Msh[s * 16 + t] * W[j * 32 + t];
        Vsh[s * 16 + j] = acc + W[j * 32 + 16 + s];
        if (s == 0) {
            float w0 = 0.f;
#pragma unroll
            for (int t = 0; t < 16; ++t) w0 += csh[t] * W[j * 32 + t];
            w0sh[j] = bias[j] - w0;
        }
    }
    __syncthreads();

    float As[16];
#pragma unroll
    for (int s = 0; s < 16; ++s)
        As[s] = data[(size_t)(b * 16 + s) * 2048 + f];
#pragma unroll
    for (int j = 0; j < 16; ++j) {
        float p = w0sh[j];
#pragma unroll
        for (int s = 0; s < 16; ++s) p += As[s] * Vsh[s * 16 + j];
        float e = __builtin_amdgcn_exp2f(-LOG2E * p);
        float gate = __builtin_amdgcn_rcpf(1.0f + e);
        size_t r = (size_t)(j * 32 + b) * 2048 + f;
        out[r] = gate * data[r];
    }
}

extern "C" void kernel_launch(void* const* d_in, const int* in_sizes, int n_in,
                              void* d_out, int out_size, void* d_ws, size_t ws_size,
                              hipStream_t stream) {
    const float* data = (const float*)d_in[0];
    const float* attn = (const float*)d_in[1];
    const float* W    = (const float*)d_in[2];
    const float* bias = (const float*)d_in[3];
    float* out = (float*)d_out;
    float* ws  = (float*)d_ws;

    // big layout: Lpart[4][32][2048] | Mpart[8][32][256] | cpart[8][32][16]
    const size_t LP = 4 * 32 * 2048;              // 262144
    const size_t need_big = LP + 65536 + 4096;

    if (ws_size >= need_big * sizeof(float)) {
        float* Lpart = ws;
        float* Mpart = ws + LP;
        float* cpart = Mpart + 65536;
        kA<false><<<dim3(16, 4, 32), 256, 0, stream>>>(data, attn, Lpart);
        kTail<<<dim3(8, 32), 256, 0, stream>>>(attn, Lpart, 4, Mpart, cpart);
        kC2<<<dim3(8, 32), 256, 0, stream>>>(data, Mpart, cpart, W, bias, out);
    } else {
        float* Lsum  = ws;            // 65536
        float* Mpart = ws + 65536;
        float* cpart = Mpart + 65536;
        hipMemsetAsync(Lsum, 0, 65536 * sizeof(float), stream);
        kA<true><<<dim3(16, 4, 32), 256, 0, stream>>>(data, attn, Lsum);
        kTail<<<dim3(8, 32), 256, 0, stream>>>(attn, Lsum, 1, Mpart, cpart);
        kC2<<<dim3(8, 32), 256, 0, stream>>>(data, Mpart, cpart, W, bias, out);
    }
}